// Round 5
// baseline (308.385 us; speedup 1.0000x reference)
//
#include <hip/hip_runtime.h>
#include <hip/hip_bf16.h>
#include <hip/hip_cooperative_groups.h>

#define N_PTS   131072
#define N_FEATS 1000
#define FDIM    64
#define HID     128
#define NCHUNK  32
#define NTILES  (N_PTS/128)
#define PI_F    3.14159265358979f
#define LN2F    0.6931471805599453f
#define INVLN2F 1.4426950408889634f
#define EPS2    4.805e-13f            // 1e-12 * ln2^2

typedef short  short8  __attribute__((ext_vector_type(8)));   // bf16 A/B frag
typedef float  floatx4 __attribute__((ext_vector_type(4)));   // C/D frag
typedef float  f4      __attribute__((ext_vector_type(4)));
typedef float  f2      __attribute__((ext_vector_type(2)));   // -> v_pk_*_f32

__device__ __forceinline__ unsigned short f2bf(float f) {     // RNE
    unsigned int u = __float_as_uint(f);
    u = (u + 0x7FFFu + ((u >> 16) & 1u)) >> 16;
    return (unsigned short)u;
}
__device__ __forceinline__ float bf2f(unsigned short h) {
    return __uint_as_float(((unsigned int)h) << 16);
}
__device__ __forceinline__ unsigned int packbf2(float a, float b) {
    float2 t; t.x = a; t.y = b;
    __hip_bfloat162 h = __float22bfloat162_rn(t);
    union { __hip_bfloat162 hh; unsigned int u; } cv; cv.hh = h;
    return cv.u;
}
__device__ __forceinline__ float exp2_hw(float x) {           // v_exp_f32 = exp2
    float r; asm("v_exp_f32 %0, %1" : "=v"(r) : "v"(x)); return r;
}
// shared by pass1/pass2 so the max-winner recomputes identically
__device__ __forceinline__ f2 dot_s(f4 L, f2 X0, f2 X1, f2 X2) {
    f2 l0 = {L[0], L[0]}, l1 = {L[1], L[1]}, l2 = {L[2], L[2]}, hb = {L[3], L[3]};
    return X0*l0 + X1*l1 + X2*l2 - hb;    // contracts to v_pk_fma_f32 chain
}

// One cooperative kernel: grid-stride prep -> grid.sync -> persistent main loop.
__global__ __launch_bounds__(256, 2)
void afvsrn_one(const float* __restrict__ x,
                const float* __restrict__ locs, const float* __restrict__ fv,
                const float* __restrict__ W0, const float* __restrict__ b0,
                const float* __restrict__ W1, const float* __restrict__ b1,
                const float* __restrict__ W2, const float* __restrict__ b2,
                const float* __restrict__ W3, const float* __restrict__ b3,
                const float* __restrict__ W4, const float* __restrict__ b4,
                float* __restrict__ LA,               // ws: [1024] f4 {lx,ly,lz,h}*ln2
                unsigned short* __restrict__ fvB,     // ws: B-frag bf16 fv
                unsigned short* __restrict__ WB,      // ws: B-frag bf16 W0..W3
                float* __restrict__ out)
{
    __shared__ unsigned short act[128 * 136];   // [128 pts][128+8 pad] bf16, 34.8 KB

    // ---------------- phase 0: prep (grid-stride) ----------------
    for (int gid = blockIdx.x * 256 + threadIdx.x; gid < 132096; gid += gridDim.x * 256) {
        if (gid < 65536) {                             // fvB [cq][n=0..63][j=0..7]
            int j = gid & 7, n = (gid >> 3) & 63, cq = gid >> 9;
            int f = (cq >> 2) * 32 + (cq & 3) * 8 + j;
            float v = (f < N_FEATS) ? fv[f*FDIM + n] : 0.f;
            fvB[gid] = f2bf(v);
        } else if (gid < 131072) {                     // WB 4x [cq][n=0..127][j]
            int r = gid - 65536;
            int L = r >> 14, rr = r & 16383;
            int j = rr & 7, n = (rr >> 3) & 127, cq = rr >> 10;
            int k = (cq >> 2) * 32 + (cq & 3) * 8 + j;
            const float* W = (L == 0) ? W0 : (L == 1) ? W1 : (L == 2) ? W2 : W3;
            int Kin = (L == 0) ? 100 : 128;
            float v = (k < Kin) ? W[n*Kin + k] : 0.f;
            WB[r] = f2bf(v);
        } else {                                       // LA: ln2-scaled coords + h
            int t = gid - 131072;
            f4 o;
            if (t < N_FEATS) {
                float lx = locs[t*3+0] * LN2F;
                float ly = locs[t*3+1] * LN2F;
                float lz = locs[t*3+2] * LN2F;
                o[0] = lx; o[1] = ly; o[2] = lz;
                o[3] = 0.5f * (lx*lx + ly*ly + lz*lz);
            } else {                                   // pad: s' = -1e30, never max
                o[0] = 0.f; o[1] = 0.f; o[2] = 0.f; o[3] = 1e30f;
            }
            ((f4*)LA)[t] = o;
        }
    }
    cooperative_groups::this_grid().sync();

    // ---------------- persistent main loop over point tiles ----------------
    const int lane = threadIdx.x & 63;
    const int wv   = threadIdx.x >> 6;
    const int ptl  = lane & 15;
    const int quad = lane >> 4;
    const f4* LA4  = (const f4*)LA;

    for (int tile = blockIdx.x; tile < NTILES; tile += gridDim.x) {
    const int pt0 = tile * 128 + wv * 32 + ptl;       // point group A
    const int pt1 = pt0 + 16;                          // point group B

    const float xa0 = x[pt0*3+0]*LN2F, xa1 = x[pt0*3+1]*LN2F, xa2 = x[pt0*3+2]*LN2F;
    const float xb0 = x[pt1*3+0]*LN2F, xb1 = x[pt1*3+1]*LN2F, xb2 = x[pt1*3+2]*LN2F;
    const f2 X0 = {xa0, xb0}, X1 = {xa1, xb1}, X2 = {xa2, xb2};
    const f2 XX = {fmaf(xa0, xa0, fmaf(xa1, xa1, xa2*xa2)),
                   fmaf(xb0, xb0, fmaf(xb1, xb1, xb2*xb2))};

    // ---------- pass 1: packed smax (no transcendentals) ----------
    f2 sm = {-1e30f, -1e30f};
    #pragma unroll 2
    for (int c = 0; c < NCHUNK; ++c) {
        const f4* lp = LA4 + c*32 + quad*8;
        #pragma unroll
        for (int j = 0; j < 8; ++j)
            sm = __builtin_elementwise_max(sm, dot_s(lp[j], X0, X1, X2));
    }
    float sma = sm[0], smb = sm[1];
    sma = fmaxf(sma, __shfl_xor(sma, 16)); sma = fmaxf(sma, __shfl_xor(sma, 32));
    smb = fmaxf(smb, __shfl_xor(smb, 16)); smb = fmaxf(smb, __shfl_xor(smb, 32));
    const float ma = __builtin_amdgcn_rsqf(fmaxf(fmaf(-2.f, sma, XX[0]), EPS2));
    const float mb = __builtin_amdgcn_rsqf(fmaxf(fmaf(-2.f, smb, XX[1]), EPS2));

    // ---------- pass 2: p = exp2(inv'-m') into A-frags; feats = w @ fv ----------
    floatx4 accA[4] = {}; floatx4 accB[4] = {};
    f2 lsv = {0.f, 0.f};
    const f2 eps2v = {EPS2, EPS2};
    const f2 two   = {2.f, 2.f};
    for (int c = 0; c < NCHUNK; ++c) {
        const f4* lp = LA4 + c*32 + quad*8;
        const short8* bp = (const short8*)fvB + (c*4 + quad)*64;
        short8 bv0 = bp[ptl], bv1 = bp[16 + ptl], bv2 = bp[32 + ptl], bv3 = bp[48 + ptl];
        const bool padq = (c == NCHUNK-1) && (quad != 0);   // pads -> p = 0
        const f2 MQ = {padq ? 3e38f : ma, padq ? 3e38f : mb};
        float pa[8], pb[8];
        #pragma unroll
        for (int j = 0; j < 8; ++j) {
            f2 s = dot_s(lp[j], X0, X1, X2);
            f2 d = __builtin_elementwise_max(XX - two*s, eps2v);
            f2 inv = {__builtin_amdgcn_rsqf(d[0]), __builtin_amdgcn_rsqf(d[1])};
            f2 e = inv - MQ;
            pa[j] = exp2_hw(e[0]);
            pb[j] = exp2_hw(e[1]);
            f2 pj = {pa[j], pb[j]};
            lsv += pj;
        }
        union { short8 v; unsigned int u[4]; } afa, afb;
        afa.u[0] = packbf2(pa[0], pa[1]); afa.u[1] = packbf2(pa[2], pa[3]);
        afa.u[2] = packbf2(pa[4], pa[5]); afa.u[3] = packbf2(pa[6], pa[7]);
        afb.u[0] = packbf2(pb[0], pb[1]); afb.u[1] = packbf2(pb[2], pb[3]);
        afb.u[2] = packbf2(pb[4], pb[5]); afb.u[3] = packbf2(pb[6], pb[7]);
        accA[0] = __builtin_amdgcn_mfma_f32_16x16x32_bf16(afa.v, bv0, accA[0], 0, 0, 0);
        accB[0] = __builtin_amdgcn_mfma_f32_16x16x32_bf16(afb.v, bv0, accB[0], 0, 0, 0);
        accA[1] = __builtin_amdgcn_mfma_f32_16x16x32_bf16(afa.v, bv1, accA[1], 0, 0, 0);
        accB[1] = __builtin_amdgcn_mfma_f32_16x16x32_bf16(afb.v, bv1, accB[1], 0, 0, 0);
        accA[2] = __builtin_amdgcn_mfma_f32_16x16x32_bf16(afa.v, bv2, accA[2], 0, 0, 0);
        accB[2] = __builtin_amdgcn_mfma_f32_16x16x32_bf16(afb.v, bv2, accB[2], 0, 0, 0);
        accA[3] = __builtin_amdgcn_mfma_f32_16x16x32_bf16(afa.v, bv3, accA[3], 0, 0, 0);
        accB[3] = __builtin_amdgcn_mfma_f32_16x16x32_bf16(afb.v, bv3, accB[3], 0, 0, 0);
    }
    float lsa = lsv[0], lsb = lsv[1];
    lsa += __shfl_xor(lsa, 16); lsa += __shfl_xor(lsa, 32);
    lsb += __shfl_xor(lsb, 16); lsb += __shfl_xor(lsb, 32);
    const float linva = __builtin_amdgcn_rcpf(lsa);
    const float linvb = __builtin_amdgcn_rcpf(lsb);

    // ---------- stage y = [PE(36) | feats(64) | zero pad] into LDS ----------
    const int rowA = (wv*32 + ptl) * 136;
    const int rowB = (wv*32 + 16 + ptl) * 136;
    *(short8*)&act[rowA + 96 + quad*8] = (short8)0;
    *(short8*)&act[rowB + 96 + quad*8] = (short8)0;

    #pragma unroll
    for (int i = 0; i < 9; ++i) {
        int k = quad*9 + i;
        int d = k / 12, r12 = k % 12, l = r12 % 6;
        float xva = ((d == 0) ? xa0 : (d == 1) ? xa1 : xa2) * INVLN2F;
        float xvb = ((d == 0) ? xb0 : (d == 1) ? xb1 : xb2) * INVLN2F;
        float fr = PI_F * (float)(1 << l);
        float va = (r12 < 6) ? __sinf(xva*fr) : __cosf(xva*fr);
        float vb = (r12 < 6) ? __sinf(xvb*fr) : __cosf(xvb*fr);
        act[rowA + k] = f2bf(va);
        act[rowB + k] = f2bf(vb);
    }

    float lra[4], lrb[4];
    #pragma unroll
    for (int r = 0; r < 4; ++r) {
        lra[r] = __shfl(linva, quad*4 + r);
        lrb[r] = __shfl(linvb, quad*4 + r);
    }
    #pragma unroll
    for (int nt = 0; nt < 4; ++nt)
        #pragma unroll
        for (int r = 0; r < 4; ++r) {
            act[(wv*32 + quad*4 + r)*136      + 36 + nt*16 + ptl] = f2bf(accA[nt][r] * lra[r]);
            act[(wv*32 + 16 + quad*4 + r)*136 + 36 + nt*16 + ptl] = f2bf(accB[nt][r] * lrb[r]);
        }

    // ---------- MLP layers 0..3: both point groups share each W-frag load ----------
    for (int Lyr = 0; Lyr < 4; ++Lyr) {
        const short8* WBp = (const short8*)(WB + Lyr*16384);
        const float* bL = (Lyr == 0) ? b0 : (Lyr == 1) ? b1 : (Lyr == 2) ? b2 : b3;

        short8 aA[4], aB[4];
        #pragma unroll
        for (int c = 0; c < 4; ++c) {
            aA[c] = *(const short8*)&act[rowA + c*32 + quad*8];
            aB[c] = *(const short8*)&act[rowB + c*32 + quad*8];
        }

        floatx4 acA[8] = {}, acB[8] = {};
        #pragma unroll
        for (int nt = 0; nt < 8; ++nt) {
            #pragma unroll
            for (int c = 0; c < 4; ++c) {
                short8 b = WBp[(c*4 + quad)*128 + nt*16 + ptl];
                acA[nt] = __builtin_amdgcn_mfma_f32_16x16x32_bf16(aA[c], b, acA[nt], 0, 0, 0);
                acB[nt] = __builtin_amdgcn_mfma_f32_16x16x32_bf16(aB[c], b, acB[nt], 0, 0, 0);
            }
        }
        #pragma unroll
        for (int nt = 0; nt < 8; ++nt) {
            float bias = bL[nt*16 + ptl];
            #pragma unroll
            for (int r = 0; r < 4; ++r) {
                float ha = acA[nt][r] + bias;
                float hb = acB[nt][r] + bias;
                float sa = __sinf(ha), sb = __sinf(hb);
                ha = 0.5f*ha + sa*sa;
                hb = 0.5f*hb + sb*sb;
                act[(wv*32 + quad*4 + r)*136      + nt*16 + ptl] = f2bf(ha);
                act[(wv*32 + 16 + quad*4 + r)*136 + nt*16 + ptl] = f2bf(hb);
            }
        }
    }

    // ---------- layer 4: 128 -> 1, per point group ----------
    float oa = 0.f, ob = 0.f;
    #pragma unroll
    for (int s = 0; s < 4; ++s) {
        short8 avA = *(const short8*)&act[rowA + quad*32 + s*8];
        short8 avB = *(const short8*)&act[rowB + quad*32 + s*8];
        const floatx4* wp = (const floatx4*)W4 + (quad*32 + s*8)/4;
        floatx4 w0 = wp[0], w1 = wp[1];
        oa = fmaf(bf2f((unsigned short)avA[0]), w0[0], oa);
        oa = fmaf(bf2f((unsigned short)avA[1]), w0[1], oa);
        oa = fmaf(bf2f((unsigned short)avA[2]), w0[2], oa);
        oa = fmaf(bf2f((unsigned short)avA[3]), w0[3], oa);
        oa = fmaf(bf2f((unsigned short)avA[4]), w1[0], oa);
        oa = fmaf(bf2f((unsigned short)avA[5]), w1[1], oa);
        oa = fmaf(bf2f((unsigned short)avA[6]), w1[2], oa);
        oa = fmaf(bf2f((unsigned short)avA[7]), w1[3], oa);
        ob = fmaf(bf2f((unsigned short)avB[0]), w0[0], ob);
        ob = fmaf(bf2f((unsigned short)avB[1]), w0[1], ob);
        ob = fmaf(bf2f((unsigned short)avB[2]), w0[2], ob);
        ob = fmaf(bf2f((unsigned short)avB[3]), w0[3], ob);
        ob = fmaf(bf2f((unsigned short)avB[4]), w1[0], ob);
        ob = fmaf(bf2f((unsigned short)avB[5]), w1[1], ob);
        ob = fmaf(bf2f((unsigned short)avB[6]), w1[2], ob);
        ob = fmaf(bf2f((unsigned short)avB[7]), w1[3], ob);
    }
    oa += __shfl_xor(oa, 16); oa += __shfl_xor(oa, 32);
    ob += __shfl_xor(ob, 16); ob += __shfl_xor(ob, 32);
    if (quad == 0) {
        float bb = b4[0];
        out[pt0] = oa + bb;
        out[pt1] = ob + bb;
    }
    } // tile loop
}

extern "C" void kernel_launch(void* const* d_in, const int* in_sizes, int n_in,
                              void* d_out, int out_size, void* d_ws, size_t ws_size,
                              hipStream_t stream)
{
    const float* x  = (const float*)d_in[0];
    const float* lc = (const float*)d_in[1];
    const float* fv = (const float*)d_in[2];
    const float* W0 = (const float*)d_in[3];
    const float* b0 = (const float*)d_in[4];
    const float* W1 = (const float*)d_in[5];
    const float* b1 = (const float*)d_in[6];
    const float* W2 = (const float*)d_in[7];
    const float* b2 = (const float*)d_in[8];
    const float* W3 = (const float*)d_in[9];
    const float* b3 = (const float*)d_in[10];
    const float* W4 = (const float*)d_in[11];
    const float* b4 = (const float*)d_in[12];

    char* ws = (char*)d_ws;
    float*          LAp  = (float*)ws;                              // 16 KB
    unsigned short* fvBp = (unsigned short*)(ws + 16384);           // 128 KB
    unsigned short* WBp  = (unsigned short*)(ws + 16384 + 131072);  // 128 KB
    float*          outp = (float*)d_out;

    // Occupancy-sized persistent grid: cooperative launch is guaranteed to fit.
    // (Host-only queries; deterministic per environment; graph-capture-safe.)
    int dev = 0; hipGetDevice(&dev);
    int numCU = 256;
    hipDeviceGetAttribute(&numCU, hipDeviceAttributeMultiprocessorCount, dev);
    int maxB = 0;
    hipOccupancyMaxActiveBlocksPerMultiprocessor(&maxB, (const void*)afvsrn_one, 256, 0);
    if (maxB < 1) maxB = 1;
    long long g = (long long)numCU * maxB;
    int grid = (g > NTILES) ? NTILES : (int)g;

    void* args[] = {
        (void*)&x,  (void*)&lc, (void*)&fv,
        (void*)&W0, (void*)&b0, (void*)&W1, (void*)&b1,
        (void*)&W2, (void*)&b2, (void*)&W3, (void*)&b3,
        (void*)&W4, (void*)&b4,
        (void*)&LAp, (void*)&fvBp, (void*)&WBp, (void*)&outp
    };
    hipLaunchCooperativeKernel((const void*)afvsrn_one, dim3(grid), dim3(256),
                               (void**)args, 0, stream);
}

// Round 6
// 259.668 us; speedup vs baseline: 1.1876x; 1.1876x over previous
//
#include <hip/hip_runtime.h>
#include <hip/hip_bf16.h>

#define N_PTS   131072
#define N_FEATS 1000
#define FDIM    64
#define HID     128
#define NCHUNK  32
#define PI_F    3.14159265358979f
#define LN2F    0.6931471805599453f
#define EPS2    4.805e-13f            // 1e-12 * ln2^2

typedef short  short8  __attribute__((ext_vector_type(8)));   // bf16 A/B frag
typedef float  floatx4 __attribute__((ext_vector_type(4)));   // C/D frag
typedef float  f4      __attribute__((ext_vector_type(4)));
typedef float  f2      __attribute__((ext_vector_type(2)));   // -> v_pk_*_f32

__device__ __forceinline__ unsigned short f2bf(float f) {     // RNE
    unsigned int u = __float_as_uint(f);
    u = (u + 0x7FFFu + ((u >> 16) & 1u)) >> 16;
    return (unsigned short)u;
}
__device__ __forceinline__ float bf2f(unsigned short h) {
    return __uint_as_float(((unsigned int)h) << 16);
}
__device__ __forceinline__ unsigned int packbf2(float a, float b) {
    float2 t; t.x = a; t.y = b;
    __hip_bfloat162 h = __float22bfloat162_rn(t);
    union { __hip_bfloat162 hh; unsigned int u; } cv; cv.hh = h;
    return cv.u;
}
__device__ __forceinline__ float exp2_hw(float x) {           // v_exp_f32 = exp2
    float r; asm("v_exp_f32 %0, %1" : "=v"(r) : "v"(x)); return r;
}
// s for a FEATURE PAIR of one point: 3 pk_fma. v0={lx0,lx1,ly0,ly1} v1={lz0,lz1,h0,h1}
__device__ __forceinline__ f2 dot_pair(f4 v0, f4 v1, f2 X0, f2 X1, f2 X2) {
    f2 a = {v0[0], v0[1]}, b = {v0[2], v0[3]};
    f2 c = {v1[0], v1[1]}, h = {v1[2], v1[3]};
    return X0*a + X1*b + X2*c - h;
}

// ---------------- prep: feature-pair LA + bf16 fragment-ordered fv / W ----------------
// gid <  65536 : fvB [cq=chunk*4+quad][n=0..63][j=0..7]
// gid < 131072 : WB 4 layers [cq][n=0..127][j=0..7], layer0 K padded 100->128
// gid < 131584 : LA 512 feature-pairs {lx0,lx1,ly0,ly1,lz0,lz1,h0,h1}, ln2-scaled
__global__ void prep_all(const float* __restrict__ locs, const float* __restrict__ fv,
                         const float* __restrict__ W0, const float* __restrict__ W1,
                         const float* __restrict__ W2, const float* __restrict__ W3,
                         float* __restrict__ LA, unsigned short* __restrict__ fvB,
                         unsigned short* __restrict__ WB)
{
    int gid = blockIdx.x * 256 + threadIdx.x;
    if (gid < 65536) {
        int j = gid & 7, n = (gid >> 3) & 63, cq = gid >> 9;
        int f = (cq >> 2) * 32 + (cq & 3) * 8 + j;
        float v = (f < N_FEATS) ? fv[f*FDIM + n] : 0.f;
        fvB[gid] = f2bf(v);
    } else if (gid < 131072) {
        int r = gid - 65536;
        int L = r >> 14, rr = r & 16383;
        int j = rr & 7, n = (rr >> 3) & 127, cq = rr >> 10;
        int k = (cq >> 2) * 32 + (cq & 3) * 8 + j;
        const float* W = (L == 0) ? W0 : (L == 1) ? W1 : (L == 2) ? W2 : W3;
        int Kin = (L == 0) ? 100 : 128;
        float v = (k < Kin) ? W[n*Kin + k] : 0.f;
        WB[r] = f2bf(v);
    } else if (gid < 131584) {
        int t = gid - 131072;                 // pair index 0..511
        float o[8];
        #pragma unroll
        for (int s = 0; s < 2; ++s) {
            int f = 2*t + s;
            if (f < N_FEATS) {
                float lx = locs[f*3+0] * LN2F;
                float ly = locs[f*3+1] * LN2F;
                float lz = locs[f*3+2] * LN2F;
                o[0+s] = lx; o[2+s] = ly; o[4+s] = lz;
                o[6+s] = 0.5f * (lx*lx + ly*ly + lz*lz);
            } else {                          // pad: s' = -1e30, never the max
                o[0+s] = 0.f; o[2+s] = 0.f; o[4+s] = 0.f; o[6+s] = 1e30f;
            }
        }
        f4* LAo = (f4*)(LA + t*8);
        LAo[0] = (f4){o[0], o[1], o[2], o[3]};
        LAo[1] = (f4){o[4], o[5], o[6], o[7]};
    }
}

// ---------------- main fused kernel (round-3 shape: 16 pts/wave, no syncthreads) ----------------
__global__ __launch_bounds__(256, 4)
void afvsrn_mfma(const float* __restrict__ x,
                 const float* __restrict__ LA,
                 const unsigned short* __restrict__ fvB,
                 const unsigned short* __restrict__ WB,
                 const float* __restrict__ b0, const float* __restrict__ b1,
                 const float* __restrict__ b2, const float* __restrict__ b3,
                 const float* __restrict__ W4, const float* __restrict__ b4,
                 float* __restrict__ out)
{
    __shared__ unsigned short act[64 * 136];   // [64 pts][128+8 pad] bf16

    const int lane = threadIdx.x & 63;
    const int wv   = threadIdx.x >> 6;
    const int ptl  = lane & 15;                // A-frag row m / C-frag col n
    const int quad = lane >> 4;                // A/B-frag k-group, C-frag row-group
    const int ptbase = blockIdx.x * 64 + wv * 16;

    const float xr0 = x[(ptbase + ptl)*3 + 0];
    const float xr1 = x[(ptbase + ptl)*3 + 1];
    const float xr2 = x[(ptbase + ptl)*3 + 2];
    const float xa0 = xr0*LN2F, xa1 = xr1*LN2F, xa2 = xr2*LN2F;
    const float xx  = fmaf(xa0, xa0, fmaf(xa1, xa1, xa2*xa2));
    const f2 X0 = {xa0, xa0}, X1 = {xa1, xa1}, X2 = {xa2, xa2};
    const f2 XXv = {xx, xx};

    // lane's features: f = c*32 + quad*8 + j  ->  pairs  c*16 + quad*4 + {0..3}
    const f4* LAq = (const f4*)LA;             // 2 f4 per pair

    // ---------- pass 1: packed smax (no transcendentals) ----------
    f2 sm = {-1e30f, -1e30f};
    #pragma unroll 2
    for (int c = 0; c < NCHUNK; ++c) {
        const f4* lp = LAq + (c*16 + quad*4)*2;
        #pragma unroll
        for (int pr = 0; pr < 4; ++pr)
            sm = __builtin_elementwise_max(sm, dot_pair(lp[pr*2], lp[pr*2+1], X0, X1, X2));
    }
    float sma = fmaxf(sm[0], sm[1]);
    sma = fmaxf(sma, __shfl_xor(sma, 16));
    sma = fmaxf(sma, __shfl_xor(sma, 32));
    const float ma = __builtin_amdgcn_rsqf(fmaxf(fmaf(-2.f, sma, xx), EPS2));

    // ---------- pass 2: p = exp2(inv'-m') into A-frags; feats = w @ fv ----------
    floatx4 acc2[4] = {};
    f2 lsv = {0.f, 0.f};
    const f2 eps2v = {EPS2, EPS2};
    for (int c = 0; c < NCHUNK; ++c) {
        const f4* lp = LAq + (c*16 + quad*4)*2;
        const short8* bp = (const short8*)fvB + (c*4 + quad)*64;
        short8 bv0 = bp[ptl], bv1 = bp[16 + ptl], bv2 = bp[32 + ptl], bv3 = bp[48 + ptl];
        // pads are exactly quads 1..3 of the last chunk -> p = 0 via m' = 3e38
        const bool padq = (c == NCHUNK-1) && (quad != 0);
        const f2 MQ = {padq ? 3e38f : ma, padq ? 3e38f : ma};
        union { short8 v; unsigned int u[4]; } af;
        #pragma unroll
        for (int pr = 0; pr < 4; ++pr) {
            f2 s = dot_pair(lp[pr*2], lp[pr*2+1], X0, X1, X2);
            f2 d = __builtin_elementwise_max(XXv - 2.f*s, eps2v);
            f2 e = {__builtin_amdgcn_rsqf(d[0]), __builtin_amdgcn_rsqf(d[1])};
            e = e - MQ;
            f2 p = {exp2_hw(e[0]), exp2_hw(e[1])};
            lsv += p;
            af.u[pr] = packbf2(p[0], p[1]);
        }
        acc2[0] = __builtin_amdgcn_mfma_f32_16x16x32_bf16(af.v, bv0, acc2[0], 0, 0, 0);
        acc2[1] = __builtin_amdgcn_mfma_f32_16x16x32_bf16(af.v, bv1, acc2[1], 0, 0, 0);
        acc2[2] = __builtin_amdgcn_mfma_f32_16x16x32_bf16(af.v, bv2, acc2[2], 0, 0, 0);
        acc2[3] = __builtin_amdgcn_mfma_f32_16x16x32_bf16(af.v, bv3, acc2[3], 0, 0, 0);
    }
    float lsum = lsv[0] + lsv[1];
    lsum += __shfl_xor(lsum, 16);
    lsum += __shfl_xor(lsum, 32);
    const float linv = __builtin_amdgcn_rcpf(lsum);

    // ---------- stage y = [PE(36) | feats(64) | zero pad to 128] ----------
    const int myrow = (wv*16 + ptl) * 136;
    *(short8*)&act[myrow + 96 + quad*8] = (short8)0;

    #pragma unroll
    for (int i = 0; i < 9; ++i) {
        int k = quad*9 + i;
        int d = k / 12, r12 = k % 12, l = r12 % 6;
        float xv = (d == 0) ? xr0 : (d == 1) ? xr1 : xr2;
        float ang = xv * (PI_F * (float)(1 << l));
        float v = (r12 < 6) ? __sinf(ang) : __cosf(ang);
        act[myrow + k] = f2bf(v);
    }

    float linv_r[4];
    #pragma unroll
    for (int r = 0; r < 4; ++r) linv_r[r] = __shfl(linv, quad*4 + r);
    #pragma unroll
    for (int nt = 0; nt < 4; ++nt)
        #pragma unroll
        for (int r = 0; r < 4; ++r)
            act[(wv*16 + quad*4 + r)*136 + 36 + nt*16 + ptl] = f2bf(acc2[nt][r] * linv_r[r]);

    // ---------- MLP layers 0..3 via MFMA ----------
    for (int Lyr = 0; Lyr < 4; ++Lyr) {
        const short8* WBp = (const short8*)(WB + Lyr*16384);
        const float* bL = (Lyr == 0) ? b0 : (Lyr == 1) ? b1 : (Lyr == 2) ? b2 : b3;

        short8 a[4];
        #pragma unroll
        for (int c = 0; c < 4; ++c)
            a[c] = *(const short8*)&act[myrow + c*32 + quad*8];

        floatx4 acc[8] = {};
        #pragma unroll
        for (int nt = 0; nt < 8; ++nt) {
            #pragma unroll
            for (int c = 0; c < 4; ++c) {
                short8 b = WBp[(c*4 + quad)*128 + nt*16 + ptl];
                acc[nt] = __builtin_amdgcn_mfma_f32_16x16x32_bf16(a[c], b, acc[nt], 0, 0, 0);
            }
        }
        #pragma unroll
        for (int nt = 0; nt < 8; ++nt) {
            float bias = bL[nt*16 + ptl];
            #pragma unroll
            for (int r = 0; r < 4; ++r) {
                float h = acc[nt][r] + bias;
                float s = __sinf(h);
                h = 0.5f*h + s*s;                       // SnakeAlt
                act[(wv*16 + quad*4 + r)*136 + nt*16 + ptl] = f2bf(h);
            }
        }
    }

    // ---------- layer 4: 128 -> 1 ----------
    float o = 0.f;
    #pragma unroll
    for (int s = 0; s < 4; ++s) {
        short8 av = *(const short8*)&act[myrow + quad*32 + s*8];
        const floatx4* wp = (const floatx4*)W4 + (quad*32 + s*8)/4;
        floatx4 w0 = wp[0], w1 = wp[1];
        o = fmaf(bf2f((unsigned short)av[0]), w0[0], o);
        o = fmaf(bf2f((unsigned short)av[1]), w0[1], o);
        o = fmaf(bf2f((unsigned short)av[2]), w0[2], o);
        o = fmaf(bf2f((unsigned short)av[3]), w0[3], o);
        o = fmaf(bf2f((unsigned short)av[4]), w1[0], o);
        o = fmaf(bf2f((unsigned short)av[5]), w1[1], o);
        o = fmaf(bf2f((unsigned short)av[6]), w1[2], o);
        o = fmaf(bf2f((unsigned short)av[7]), w1[3], o);
    }
    o += __shfl_xor(o, 16);
    o += __shfl_xor(o, 32);
    if (quad == 0) out[ptbase + ptl] = o + b4[0];
}

extern "C" void kernel_launch(void* const* d_in, const int* in_sizes, int n_in,
                              void* d_out, int out_size, void* d_ws, size_t ws_size,
                              hipStream_t stream)
{
    const float* x  = (const float*)d_in[0];
    const float* lc = (const float*)d_in[1];
    const float* fv = (const float*)d_in[2];
    const float* W0 = (const float*)d_in[3];
    const float* b0 = (const float*)d_in[4];
    const float* W1 = (const float*)d_in[5];
    const float* b1 = (const float*)d_in[6];
    const float* W2 = (const float*)d_in[7];
    const float* b2 = (const float*)d_in[8];
    const float* W3 = (const float*)d_in[9];
    const float* b3 = (const float*)d_in[10];
    const float* W4 = (const float*)d_in[11];
    const float* b4 = (const float*)d_in[12];

    char* ws = (char*)d_ws;
    float*          LAp = (float*)ws;                               // 16 KB
    unsigned short* fvB = (unsigned short*)(ws + 16384);            // 128 KB
    unsigned short* WB  = (unsigned short*)(ws + 16384 + 131072);   // 128 KB

    prep_all<<<dim3(514), dim3(256), 0, stream>>>(lc, fv, W0, W1, W2, W3,
                                                  LAp, fvB, WB);

    afvsrn_mfma<<<dim3(N_PTS/64), dim3(256), 0, stream>>>(
        x, LAp, fvB, WB, b0, b1, b2, b3, W4, b4, (float*)d_out);
}

// Round 8
// 257.822 us; speedup vs baseline: 1.1961x; 1.0072x over previous
//
#include <hip/hip_runtime.h>
#include <hip/hip_bf16.h>

#define N_PTS   131072
#define N_FEATS 1000
#define FDIM    64
#define HID     128
#define NCHUNK  32
#define PI_F    3.14159265358979f
#define LN2F    0.6931471805599453f
#define EPS2    4.805e-13f            // 1e-12 * ln2^2

typedef short  short8  __attribute__((ext_vector_type(8)));   // bf16 A/B frag
typedef float  floatx4 __attribute__((ext_vector_type(4)));   // C/D frag
typedef float  f4      __attribute__((ext_vector_type(4)));
typedef float  f2      __attribute__((ext_vector_type(2)));   // -> v_pk_*_f32

__device__ __forceinline__ unsigned short f2bf(float f) {     // RNE
    unsigned int u = __float_as_uint(f);
    u = (u + 0x7FFFu + ((u >> 16) & 1u)) >> 16;
    return (unsigned short)u;
}
__device__ __forceinline__ float bf2f(unsigned short h) {
    return __uint_as_float(((unsigned int)h) << 16);
}
__device__ __forceinline__ unsigned int packbf2(float a, float b) {
    float2 t; t.x = a; t.y = b;
    __hip_bfloat162 h = __float22bfloat162_rn(t);
    union { __hip_bfloat162 hh; unsigned int u; } cv; cv.hh = h;
    return cv.u;
}
__device__ __forceinline__ float exp2_hw(float x) {           // v_exp_f32 = exp2
    float r; asm("v_exp_f32 %0, %1" : "=v"(r) : "v"(x)); return r;
}
// s for a FEATURE PAIR of one point: v0={lx0,lx1,ly0,ly1} v1={lz0,lz1,h0,h1}
__device__ __forceinline__ f2 dot_pair(f4 v0, f4 v1, f2 X0, f2 X1, f2 X2) {
    f2 a = {v0[0], v0[1]}, b = {v0[2], v0[3]};
    f2 c = {v1[0], v1[1]}, h = {v1[2], v1[3]};
    return X0*a + X1*b + X2*c - h;
}

// ---------------- prep (unchanged from r6) ----------------
__global__ void prep_all(const float* __restrict__ locs, const float* __restrict__ fv,
                         const float* __restrict__ W0, const float* __restrict__ W1,
                         const float* __restrict__ W2, const float* __restrict__ W3,
                         float* __restrict__ LA, unsigned short* __restrict__ fvB,
                         unsigned short* __restrict__ WB)
{
    int gid = blockIdx.x * 256 + threadIdx.x;
    if (gid < 65536) {
        int j = gid & 7, n = (gid >> 3) & 63, cq = gid >> 9;
        int f = (cq >> 2) * 32 + (cq & 3) * 8 + j;
        float v = (f < N_FEATS) ? fv[f*FDIM + n] : 0.f;
        fvB[gid] = f2bf(v);
    } else if (gid < 131072) {
        int r = gid - 65536;
        int L = r >> 14, rr = r & 16383;
        int j = rr & 7, n = (rr >> 3) & 127, cq = rr >> 10;
        int k = (cq >> 2) * 32 + (cq & 3) * 8 + j;
        const float* W = (L == 0) ? W0 : (L == 1) ? W1 : (L == 2) ? W2 : W3;
        int Kin = (L == 0) ? 100 : 128;
        float v = (k < Kin) ? W[n*Kin + k] : 0.f;
        WB[r] = f2bf(v);
    } else if (gid < 131584) {
        int t = gid - 131072;                 // pair index 0..511
        float o[8];
        #pragma unroll
        for (int s = 0; s < 2; ++s) {
            int f = 2*t + s;
            if (f < N_FEATS) {
                float lx = locs[f*3+0] * LN2F;
                float ly = locs[f*3+1] * LN2F;
                float lz = locs[f*3+2] * LN2F;
                o[0+s] = lx; o[2+s] = ly; o[4+s] = lz;
                o[6+s] = 0.5f * (lx*lx + ly*ly + lz*lz);
            } else {                          // pad: s' = -1e30, never the max
                o[0+s] = 0.f; o[2+s] = 0.f; o[4+s] = 0.f; o[6+s] = 1e30f;
            }
        }
        f4* LAo = (f4*)(LA + t*8);
        LAo[0] = (f4){o[0], o[1], o[2], o[3]};
        LAo[1] = (f4){o[4], o[5], o[6], o[7]};
    }
}

// ---------------- main fused kernel ----------------
// 16 pts/wave, no __syncthreads. r8 = r7 with the MLP WAR hazard fixed:
// layer input fragments are loaded ONCE into registers before either half writes.
__global__ __launch_bounds__(256, 4)
void afvsrn_mfma(const float* __restrict__ x,
                 const float* __restrict__ LA,
                 const unsigned short* __restrict__ fvB,
                 const unsigned short* __restrict__ WB,
                 const float* __restrict__ b0, const float* __restrict__ b1,
                 const float* __restrict__ b2, const float* __restrict__ b3,
                 const float* __restrict__ W4, const float* __restrict__ b4,
                 float* __restrict__ out)
{
    __shared__ unsigned short act[64 * 136];   // [64 pts][128+8 pad] bf16

    const int lane = threadIdx.x & 63;
    const int wv   = threadIdx.x >> 6;
    const int ptl  = lane & 15;                // A-frag row m / C-frag col n
    const int quad = lane >> 4;                // A/B-frag k-group, C-frag row-group
    const int ptbase = blockIdx.x * 64 + wv * 16;

    const float xr0 = x[(ptbase + ptl)*3 + 0];
    const float xr1 = x[(ptbase + ptl)*3 + 1];
    const float xr2 = x[(ptbase + ptl)*3 + 2];
    const float xa0 = xr0*LN2F, xa1 = xr1*LN2F, xa2 = xr2*LN2F;
    const float xx  = fmaf(xa0, xa0, fmaf(xa1, xa1, xa2*xa2));
    const f2 X0 = {xa0, xa0}, X1 = {xa1, xa1}, X2 = {xa2, xa2};
    const f2 XXv = {xx, xx};

    const f4* LAq = (const f4*)LA;             // 2 f4 per feature pair

    // ---------- pass 1: packed smax (no transcendentals), deep unroll ----------
    f2 sm = {-1e30f, -1e30f};
    #pragma unroll 4
    for (int c = 0; c < NCHUNK; ++c) {
        const f4* lp = LAq + (c*16 + quad*4)*2;
        #pragma unroll
        for (int pr = 0; pr < 4; ++pr)
            sm = __builtin_elementwise_max(sm, dot_pair(lp[pr*2], lp[pr*2+1], X0, X1, X2));
    }
    float sma = fmaxf(sm[0], sm[1]);
    sma = fmaxf(sma, __shfl_xor(sma, 16));
    sma = fmaxf(sma, __shfl_xor(sma, 32));
    const float ma = __builtin_amdgcn_rsqf(fmaxf(fmaf(-2.f, sma, xx), EPS2));

    // ---------- pass 2: software-pipelined B loads; p straight into A-frags ----------
    floatx4 acc2[4] = {};
    f2 lsv0 = {0.f, 0.f}, lsv1 = {0.f, 0.f};
    const f2 eps2v = {EPS2, EPS2};
    const short8* bpq = (const short8*)fvB + quad*64 + ptl;   // + c*256 + nt*16
    // prologue: chunk 0's B frags in flight before any compute
    short8 nb0 = bpq[0], nb1 = bpq[16], nb2 = bpq[32], nb3 = bpq[48];
    for (int c = 0; c < NCHUNK; ++c) {
        short8 bv0 = nb0, bv1 = nb1, bv2 = nb2, bv3 = nb3;
        if (c + 1 < NCHUNK) {                  // issue next chunk's loads NOW
            const short8* bn = bpq + (c + 1)*256;
            nb0 = bn[0]; nb1 = bn[16]; nb2 = bn[32]; nb3 = bn[48];
        }
        const f4* lp = LAq + (c*16 + quad*4)*2;
        const bool padq = (c == NCHUNK-1) && (quad != 0);   // pads -> p = 0
        const f2 MQ = {padq ? 3e38f : ma, padq ? 3e38f : ma};
        union { short8 v; unsigned int u[4]; } af;
        #pragma unroll
        for (int pr = 0; pr < 4; ++pr) {
            f2 s = dot_pair(lp[pr*2], lp[pr*2+1], X0, X1, X2);
            f2 d = __builtin_elementwise_max(XXv - 2.f*s, eps2v);
            f2 e = {__builtin_amdgcn_rsqf(d[0]), __builtin_amdgcn_rsqf(d[1])};
            e = e - MQ;
            f2 p = {exp2_hw(e[0]), exp2_hw(e[1])};
            if (pr & 1) lsv1 += p; else lsv0 += p;
            af.u[pr] = packbf2(p[0], p[1]);
        }
        acc2[0] = __builtin_amdgcn_mfma_f32_16x16x32_bf16(af.v, bv0, acc2[0], 0, 0, 0);
        acc2[1] = __builtin_amdgcn_mfma_f32_16x16x32_bf16(af.v, bv1, acc2[1], 0, 0, 0);
        acc2[2] = __builtin_amdgcn_mfma_f32_16x16x32_bf16(af.v, bv2, acc2[2], 0, 0, 0);
        acc2[3] = __builtin_amdgcn_mfma_f32_16x16x32_bf16(af.v, bv3, acc2[3], 0, 0, 0);
    }
    f2 lsv = lsv0 + lsv1;
    float lsum = lsv[0] + lsv[1];
    lsum += __shfl_xor(lsum, 16);
    lsum += __shfl_xor(lsum, 32);
    const float linv = __builtin_amdgcn_rcpf(lsum);

    // ---------- stage y = [PE(36) | feats(64) | zero pad to 128] ----------
    const int myrow = (wv*16 + ptl) * 136;
    *(short8*)&act[myrow + 96 + quad*8] = (short8)0;

    #pragma unroll
    for (int i = 0; i < 9; ++i) {
        int k = quad*9 + i;
        int d = k / 12, r12 = k % 12, l = r12 % 6;
        float xv = (d == 0) ? xr0 : (d == 1) ? xr1 : xr2;
        float ang = xv * (PI_F * (float)(1 << l));
        float v = (r12 < 6) ? __sinf(ang) : __cosf(ang);
        act[myrow + k] = f2bf(v);
    }

    float linv_r[4];
    #pragma unroll
    for (int r = 0; r < 4; ++r) linv_r[r] = __shfl(linv, quad*4 + r);
    #pragma unroll
    for (int nt = 0; nt < 4; ++nt)
        #pragma unroll
        for (int r = 0; r < 4; ++r)
            act[(wv*16 + quad*4 + r)*136 + 36 + nt*16 + ptl] = f2bf(acc2[nt][r] * linv_r[r]);

    // ---------- MLP layers 0..3 via MFMA, two 4-nt halves (16 AGPR) ----------
    // Input fragments are read ONCE per layer (registers) BEFORE any half
    // writes back into act — avoids the r7 WAR hazard.
    for (int Lyr = 0; Lyr < 4; ++Lyr) {
        const short8* WBp = (const short8*)(WB + Lyr*16384);
        const float* bL = (Lyr == 0) ? b0 : (Lyr == 1) ? b1 : (Lyr == 2) ? b2 : b3;

        short8 a[4];
        #pragma unroll
        for (int c = 0; c < 4; ++c)
            a[c] = *(const short8*)&act[myrow + c*32 + quad*8];

        #pragma unroll
        for (int half = 0; half < 2; ++half) {
            floatx4 acc[4] = {};
            #pragma unroll
            for (int nt4 = 0; nt4 < 4; ++nt4) {
                const int nt = half*4 + nt4;
                #pragma unroll
                for (int c = 0; c < 4; ++c) {
                    short8 b = WBp[(c*4 + quad)*128 + nt*16 + ptl];
                    acc[nt4] = __builtin_amdgcn_mfma_f32_16x16x32_bf16(a[c], b, acc[nt4], 0, 0, 0);
                }
            }
            #pragma unroll
            for (int nt4 = 0; nt4 < 4; ++nt4) {
                const int nt = half*4 + nt4;
                float bias = bL[nt*16 + ptl];
                #pragma unroll
                for (int r = 0; r < 4; ++r) {
                    float h = acc[nt4][r] + bias;
                    float s = __sinf(h);
                    h = 0.5f*h + s*s;                   // SnakeAlt
                    act[(wv*16 + quad*4 + r)*136 + nt*16 + ptl] = f2bf(h);
                }
            }
        }
    }

    // ---------- layer 4: 128 -> 1 ----------
    float o = 0.f;
    #pragma unroll
    for (int s = 0; s < 4; ++s) {
        short8 av = *(const short8*)&act[myrow + quad*32 + s*8];
        const floatx4* wp = (const floatx4*)W4 + (quad*32 + s*8)/4;
        floatx4 w0 = wp[0], w1 = wp[1];
        o = fmaf(bf2f((unsigned short)av[0]), w0[0], o);
        o = fmaf(bf2f((unsigned short)av[1]), w0[1], o);
        o = fmaf(bf2f((unsigned short)av[2]), w0[2], o);
        o = fmaf(bf2f((unsigned short)av[3]), w0[3], o);
        o = fmaf(bf2f((unsigned short)av[4]), w1[0], o);
        o = fmaf(bf2f((unsigned short)av[5]), w1[1], o);
        o = fmaf(bf2f((unsigned short)av[6]), w1[2], o);
        o = fmaf(bf2f((unsigned short)av[7]), w1[3], o);
    }
    o += __shfl_xor(o, 16);
    o += __shfl_xor(o, 32);
    if (quad == 0) out[ptbase + ptl] = o + b4[0];
}

extern "C" void kernel_launch(void* const* d_in, const int* in_sizes, int n_in,
                              void* d_out, int out_size, void* d_ws, size_t ws_size,
                              hipStream_t stream)
{
    const float* x  = (const float*)d_in[0];
    const float* lc = (const float*)d_in[1];
    const float* fv = (const float*)d_in[2];
    const float* W0 = (const float*)d_in[3];
    const float* b0 = (const float*)d_in[4];
    const float* W1 = (const float*)d_in[5];
    const float* b1 = (const float*)d_in[6];
    const float* W2 = (const float*)d_in[7];
    const float* b2 = (const float*)d_in[8];
    const float* W3 = (const float*)d_in[9];
    const float* b3 = (const float*)d_in[10];
    const float* W4 = (const float*)d_in[11];
    const float* b4 = (const float*)d_in[12];

    char* ws = (char*)d_ws;
    float*          LAp = (float*)ws;                               // 16 KB
    unsigned short* fvB = (unsigned short*)(ws + 16384);            // 128 KB
    unsigned short* WB  = (unsigned short*)(ws + 16384 + 131072);   // 128 KB

    prep_all<<<dim3(514), dim3(256), 0, stream>>>(lc, fv, W0, W1, W2, W3,
                                                  LAp, fvB, WB);

    afvsrn_mfma<<<dim3(N_PTS/64), dim3(256), 0, stream>>>(
        x, LAp, fvB, WB, b0, b1, b2, b3, W4, b4, (float*)d_out);
}